// Round 15
// baseline (269.440 us; speedup 1.0000x reference)
//
#include <hip/hip_runtime.h>

#define B_ 32
#define L_ 2048
#define C1 512      // conv1 out channels (2C)
#define C2 256      // conv2 out channels
#define KW 15
#define P1 2034     // conv1 valid positions (L-14)
#define NJ 2016     // conv2 positions actually used (pos 2..2017)
#define NSEC 252
#define GOD 256

typedef _Float16 f16;
typedef __attribute__((ext_vector_type(4))) _Float16 f16x4;
typedef __attribute__((ext_vector_type(8))) _Float16 f16x8;
typedef __attribute__((ext_vector_type(4))) float f32x4;

// workspace byte offsets
#define WS_Y1T   0ull                       // f16 [32][2034][512]  = 66,650,112 B
#define WS_W2R   66650112ull                // f16 [15][256][512]   =  3,932,160 B
#define WS_W1R   70582272ull                // f16 [512][104]       =    106,496 B
#define WS_E     70688768ull                // f16 [32][256][2016]  = 33,030,144 B
#define WS_V     103718912ull               // f32 [32][2048]       =    262,144 B
#define WS_EN    103981056ull               // f32 [32][252]        =     32,256 B

__device__ __forceinline__ void gl16(const f16* g, f16* l) {
    __builtin_amdgcn_global_load_lds((const __attribute__((address_space(1))) char*)(g),
                                     (__attribute__((address_space(3))) char*)(l), 16, 0, 0);
}

// ---------------- prep | k_v fused (zero-LDS roles, concurrent) ----------------
//   [0,512)  : w2[o][c][k] f32 -> w2r[k][o][c] f16 ; w1 -> w1r[o][104] ; energies = 0
//   [512,768): v[b][p] = go_table[goidx[b]] . attn_w[:,p]
__global__ __launch_bounds__(256) void k_prep(const float* __restrict__ w2,
                                              f16* __restrict__ w2r,
                                              const float* __restrict__ w1,
                                              f16* __restrict__ w1r,
                                              float* __restrict__ energies,
                                              const int* __restrict__ goidx,
                                              const float* __restrict__ go_table,
                                              const float* __restrict__ attn_w,
                                              float* __restrict__ v) {
    const int bid = blockIdx.x;
    const int tid = threadIdx.x;
    if (bid < 512) {
        const int t0 = bid * 256 + tid;
        const int nthr = 512 * 256;
        for (int idx = t0; idx < C2 * C1 * KW; idx += nthr) {
            int o = idx / (C1 * KW);
            int rem = idx - o * (C1 * KW);
            int c = rem / KW;
            int k = rem - c * KW;
            w2r[((size_t)k * C2 + o) * C1 + c] = (f16)w2[idx];
        }
        for (int idx = t0; idx < C1 * 104; idx += nthr) {
            int o = idx / 104;
            int col = idx - o * 104;
            int e = col >> 4, k = col & 15;
            float val = (e < 5 && k < 15) ? w1[o * 75 + e * 15 + k] : 0.f;
            w1r[idx] = (f16)val;
        }
        for (int idx = t0; idx < B_ * NSEC; idx += nthr) energies[idx] = 0.f;
        return;
    }
    // k_v role
    const int r = bid - 512;
    const int b = r >> 3;
    const int p = (r & 7) * 256 + tid;
    const float* go = go_table + (size_t)goidx[b] * GOD;
    float acc = 0.f;
    for (int g = 0; g < GOD; ++g) acc = fmaf(go[g], attn_w[g * 2048 + p], acc);
    v[b * 2048 + p] = acc;
}

// ---------------- conv1 as MFMA implicit GEMM -> y1t[b][pos][o] f16 ----------------
// r12 body + LDS-staged coalesced store epilogue (16B rows). (r14, validated)
__global__ __launch_bounds__(256) void k_conv1(const int* __restrict__ seq,
                                               const float* __restrict__ aa_emb,
                                               const f16* __restrict__ w1r,
                                               const float* __restrict__ b1,
                                               f16* __restrict__ y1t) {
    __shared__ f16 Aw[256 * 104];   // 52 KB weights, rows 208 B; reused as output tile
    __shared__ f16 Bx[64 * 104];    // 13 KB, rows 208 B
    __shared__ float xs[5][80];
    const int b = blockIdx.z, o0 = blockIdx.y * 256, pos0 = blockIdx.x * 64;
    const int tid = threadIdx.x;
    const int wave = tid >> 6, lane = tid & 63;
    const int lm = lane & 15, lh = lane >> 4;
    const int half = blockIdx.y;

#pragma unroll
    for (int r = 0; r < 13; ++r) {
        int q = r * 4096 + wave * 1024 + lane * 16;
        gl16(w1r + o0 * 104 + (q >> 1), Aw + (q >> 1));
    }
    if (tid < 79) {
        int l = pos0 + tid;
        if (l < L_) {
            int a = seq[b * L_ + l];
#pragma unroll
            for (int e = 0; e < 5; ++e) xs[e][tid] = aa_emb[a * 5 + e];
        } else {
#pragma unroll
            for (int e = 0; e < 5; ++e) xs[e][tid] = 0.f;
        }
    }
    __syncthreads();
    for (int idx = tid; idx < 64 * 104; idx += 256) {
        int j = idx / 104, col = idx - j * 104;
        int e = col >> 4, k = col & 15;
        Bx[idx] = (e < 5 && k < 15) ? (f16)xs[e][j + k] : (f16)0.f;
    }
    __syncthreads();

    f32x4 acc[4][4];
#pragma unroll
    for (int mf = 0; mf < 4; ++mf)
#pragma unroll
        for (int nf = 0; nf < 4; ++nf) acc[mf][nf] = (f32x4){0.f, 0.f, 0.f, 0.f};

    const char* Ab = (const char*)Aw + (wave * 64 + lm) * 208 + lh * 16;
    const char* Bb = (const char*)Bx + lm * 208 + lh * 16;
#pragma unroll
    for (int ks = 0; ks < 3; ++ks) {
        f16x8 av[4], bv[4];
#pragma unroll
        for (int mf = 0; mf < 4; ++mf) av[mf] = *(const f16x8*)(Ab + mf * 16 * 208 + ks * 64);
#pragma unroll
        for (int nf = 0; nf < 4; ++nf) bv[nf] = *(const f16x8*)(Bb + nf * 16 * 208 + ks * 64);
#pragma unroll
        for (int mf = 0; mf < 4; ++mf)
#pragma unroll
            for (int nf = 0; nf < 4; ++nf)
                acc[mf][nf] = __builtin_amdgcn_mfma_f32_16x16x32_f16(av[mf], bv[nf], acc[mf][nf], 0, 0, 0);
    }

    // epilogue: stage tile in LDS (reuse Aw; [64 pos][264 f16] rows) -> 16B coalesced stores
    __syncthreads();   // done reading Aw frags
    {
        f16* Ot = Aw;  // 64*264 = 16896 f16 <= 26624
#pragma unroll
        for (int nf = 0; nf < 4; ++nf) {
            int pos = nf * 16 + lm;
#pragma unroll
            for (int mf = 0; mf < 4; ++mf) {
                int ob = wave * 64 + mf * 16 + lh * 4;
                f16x4 st;
#pragma unroll
                for (int rr = 0; rr < 4; ++rr)
                    st[rr] = (f16)fmaxf(acc[mf][nf][rr] + b1[o0 + ob + rr], 0.f);
                *(f16x4*)(Ot + pos * 264 + ob) = st;
            }
        }
    }
    __syncthreads();
#pragma unroll
    for (int rr = 0; rr < 8; ++rr) {
        int q = rr * 4096 + tid * 16;          // byte index in 32KB logical tile
        int pos = q >> 9;                      // /512B
        int ob = q & 511;
        if (pos0 + pos < P1)
            *(f16x8*)((char*)y1t + (size_t)(b * P1 + pos0 + pos) * 1024 + half * 512 + ob) =
                *(const f16x8*)((const char*)Aw + pos * 528 + ob);
    }
}

// ---------------- conv2 implicit GEMM, 2 barrier domains per CU (r12, validated) ----------------
// grid (16 n-tiles of 128, 32 b) = 512 blocks; block 256 = 4 waves (2M x 2N),
// wave tile 128x64. LDS 68 KB -> 2 blocks/CU (independent barrier domains; m114).
// 240 tiles of BK=32. A: 3-deep rotating 16KB slots, staged 2 tiles ahead, published
// by counted vmcnt(4) + ONE end-barrier per tile. B: single 20KB buffer per cc
// (15-tap reuse), restaged at cc boundary behind vmcnt(4)+barrier.
// Swizzles (verified r7-r14): A slot16 ^= (row>>1)&3 ; B slot16 ^= row&7.
__global__ __launch_bounds__(256, 2) void k_conv2(const f16* __restrict__ y1t,
                                                  const f16* __restrict__ w2r,
                                                  const float* __restrict__ b2,
                                                  const float* __restrict__ v,
                                                  f16* __restrict__ E,
                                                  float* __restrict__ energies) {
    __shared__ f16 As[3 * 8192];    // 48 KB: 3 slots [256 o][32 c]
    __shared__ f16 Bs[10240];       // 20 KB: [160 n][64 c]
    const int b = blockIdx.y;
    const int n0 = blockIdx.x << 7;
    const int tid = threadIdx.x;
    const int wave = tid >> 6, lane = tid & 63;
    const int lm = lane & 15, lh = lane >> 4;
    const int wm = wave >> 1, wn = wave & 1;
    const size_t ybase = (size_t)b * P1 + n0 + 2;

    f32x4 acc[8][4];
#pragma unroll
    for (int mf = 0; mf < 8; ++mf)
#pragma unroll
        for (int nf = 0; nf < 4; ++nf) acc[mf][nf] = (f32x4){0.f, 0.f, 0.f, 0.f};

#define STAGE_A(slot, cc2, k2, h2)                                                    \
    {                                                                                 \
        _Pragma("unroll")                                                             \
        for (int rr = 0; rr < 4; ++rr) {                                              \
            int q = rr * 4096 + tid * 16;                                             \
            int row = q >> 6;                                                         \
            int sw = ((q >> 4) & 3) ^ ((row >> 1) & 3);                               \
            const f16* g = w2r + (size_t)(k2) * 131072 + row * C1 + (cc2) * 64 + (h2) * 32 + sw * 8; \
            gl16(g, As + (slot) * 8192 + (q >> 1));                                   \
        }                                                                             \
    }
#define STAGE_B(cc2)                                                                  \
    {                                                                                 \
        _Pragma("unroll")                                                             \
        for (int rr = 0; rr < 5; ++rr) {                                              \
            int q = rr * 4096 + tid * 16;                                             \
            int row = q >> 7;                                                         \
            int sw = ((q >> 4) & 7) ^ (row & 7);                                      \
            const f16* g = y1t + (ybase + row) * C1 + (cc2) * 64 + sw * 8;            \
            gl16(g, Bs + (q >> 1));                                                   \
        }                                                                             \
    }

    // prologue: B(cc0) + A tiles 0,1 into slots 0,1; publish B + slot0 (leave slot1's 4)
    STAGE_B(0);
    STAGE_A(0, 0, 0, 0);
    STAGE_A(1, 0, 0, 1);
    asm volatile("s_waitcnt vmcnt(4)" ::: "memory");
    __builtin_amdgcn_s_barrier();

    const int swA = (lh ^ ((lm >> 1) & 3)) << 4;   // A read swizzle (byte)
    int sl = 0;                                    // tile t -> slot t%3

#pragma unroll 1
    for (int cc = 0; cc < 8; ++cc) {
#pragma unroll 1
        for (int k = 0; k < KW; ++k) {
#pragma unroll
            for (int h = 0; h < 2; ++h) {
                int k2 = k + 1, cc2 = cc;
                if (k2 == 15) { k2 = 0; cc2 = cc + 1; }
                const bool have2 = (cc2 < 8);
                const bool bnd = (k == 0 && h == 0 && cc > 0);
                const int s2 = (sl >= 1) ? sl - 1 : 2;   // (sl+2)%3

                if (bnd) {
                    // all B-reads of cc-1 completed before the previous end-barrier
                    STAGE_B(cc);
                    STAGE_A(s2, cc2, k2, h);   // this tile's stage, issued early
                    asm volatile("s_waitcnt vmcnt(4)" ::: "memory");  // B + prev slot published
                    __builtin_amdgcn_s_barrier();
                }

                const char* Ab = (const char*)As + sl * 16384;
                f16x8 bv[4], av[8];
#pragma unroll
                for (int nf = 0; nf < 4; ++nf) {
                    int brow = wn * 64 + nf * 16 + lm + k;
                    bv[nf] = *(const f16x8*)((const char*)Bs + brow * 128 + ((((h << 2) | lh) ^ (brow & 7)) << 4));
                }
#pragma unroll
                for (int i = 0; i < 8; ++i)
                    av[i] = *(const f16x8*)(Ab + (wm * 128 + i * 16 + lm) * 64 + swA);
                if (!bnd && have2) STAGE_A(s2, cc2, k2, h);

                __builtin_amdgcn_s_setprio(1);
#pragma unroll
                for (int i = 0; i < 8; ++i)
#pragma unroll
                    for (int nf = 0; nf < 4; ++nf)
                        acc[i][nf] = __builtin_amdgcn_mfma_f32_16x16x32_f16(av[i], bv[nf], acc[i][nf], 0, 0, 0);
                __builtin_amdgcn_s_setprio(0);
                if (have2) { asm volatile("s_waitcnt vmcnt(4)" ::: "memory"); }
                else       { asm volatile("s_waitcnt vmcnt(0)" ::: "memory"); }
                __builtin_amdgcn_s_barrier();

                sl = (sl == 2) ? 0 : sl + 1;
            }
        }
    }

    // epilogue: E store (bias+relu, f16) + fused energy partials
    const float* vb = v + b * 2048;
#pragma unroll
    for (int nf = 0; nf < 4; ++nf) {
        const int j = n0 + wn * 64 + nf * 16 + lm;
        if (j >= NJ) continue;
        const int jq = j / NSEC;
        const int jm = j - jq * NSEC;
        float esum = 0.f;
#pragma unroll
        for (int mf = 0; mf < 8; ++mf) {
            const int ob = wm * 128 + mf * 16 + lh * 4;
#pragma unroll
            for (int r = 0; r < 4; ++r) {
                float val = fmaxf(acc[mf][nf][r] + b2[ob + r], 0.f);
                E[((size_t)b * C2 + ob + r) * NJ + j] = (f16)val;
                esum = fmaf(val, vb[(ob + r) * 8 + jq], esum);
            }
        }
        atomicAdd(&energies[b * NSEC + jm], esum);
    }
#undef STAGE_A
#undef STAGE_B
}

// ---------------- ctx with fused softmax, 16 channels/block ----------------
// grid (16, 32) = 512 blocks, 256 thr = 4 waves. One softmax per block (vs 64x
// redundancy at r12's 2048 blocks), then each wave handles 4 channels x 8 rows
// of shuffle-reduced dot products against E (f16). Same 33MB read traffic.
__global__ __launch_bounds__(256) void k_ctx(const f16* __restrict__ E,
                                             const float* __restrict__ energies,
                                             float* __restrict__ out) {
    __shared__ float red[256];
    __shared__ float attn_s[NSEC];
    const int b = blockIdx.y;
    const int tid = threadIdx.x;

    float ev = 0.f, e = -1e30f;
    if (tid < NSEC) { ev = energies[b * NSEC + tid]; e = ev; }
    red[tid] = e;
    __syncthreads();
    for (int s = 128; s > 0; s >>= 1) {
        if (tid < s) red[tid] = fmaxf(red[tid], red[tid + s]);
        __syncthreads();
    }
    float m = red[0];
    __syncthreads();
    float ex = (tid < NSEC) ? __expf(ev - m) : 0.f;
    red[tid] = ex;
    __syncthreads();
    for (int s = 128; s > 0; s >>= 1) {
        if (tid < s) red[tid] += red[tid + s];
        __syncthreads();
    }
    float inv = 1.f / red[0];
    if (tid < NSEC) attn_s[tid] = ex * inv;
    __syncthreads();

    const int wave = tid >> 6, lane = tid & 63;
    float a0 = 0.f, a1 = 0.f, a2 = 0.f, a3 = 0.f;
    if (lane < 63) {
        a0 = attn_s[lane * 4];     a1 = attn_s[lane * 4 + 1];
        a2 = attn_s[lane * 4 + 2]; a3 = attn_s[lane * 4 + 3];
    }
#pragma unroll
    for (int ci = 0; ci < 4; ++ci) {
        const int c = blockIdx.x * 16 + wave * 4 + ci;
        const f16* Er = E + ((size_t)b * C2 + c) * NJ;
#pragma unroll
        for (int r = 0; r < 8; ++r) {
            float s = 0.f;
            if (lane < 63) {
                f16x4 ee = *(const f16x4*)(Er + r * NSEC + lane * 4);
                s = (float)ee[0] * a0 + (float)ee[1] * a1 + (float)ee[2] * a2 + (float)ee[3] * a3;
            }
#pragma unroll
            for (int off = 32; off > 0; off >>= 1) s += __shfl_down(s, off);
            if (lane == 0) out[b * 2048 + c * 8 + r] = s;
        }
    }
}

extern "C" void kernel_launch(void* const* d_in, const int* in_sizes, int n_in,
                              void* d_out, int out_size, void* d_ws, size_t ws_size,
                              hipStream_t stream) {
    const int*   seq      = (const int*)d_in[0];
    const int*   goidx    = (const int*)d_in[1];
    const float* aa_emb   = (const float*)d_in[2];
    const float* w1       = (const float*)d_in[3];
    const float* b1       = (const float*)d_in[4];
    const float* w2       = (const float*)d_in[5];
    const float* b2       = (const float*)d_in[6];
    const float* go_table = (const float*)d_in[7];
    const float* attn_w   = (const float*)d_in[8];
    float* out = (float*)d_out;

    char* ws = (char*)d_ws;
    f16*   y1t      = (f16*)(ws + WS_Y1T);
    f16*   w2r      = (f16*)(ws + WS_W2R);
    f16*   w1r      = (f16*)(ws + WS_W1R);
    f16*   E        = (f16*)(ws + WS_E);
    float* v        = (float*)(ws + WS_V);
    float* energies = (float*)(ws + WS_EN);

    hipLaunchKernelGGL(k_prep,  dim3(768),       dim3(256), 0, stream,
                       w2, w2r, w1, w1r, energies, goidx, go_table, attn_w, v);
    hipLaunchKernelGGL(k_conv1, dim3(32, 2, B_), dim3(256), 0, stream, seq, aa_emb, w1r, b1, y1t);
    hipLaunchKernelGGL(k_conv2, dim3(16, B_),    dim3(256), 0, stream, y1t, w2r, b2, v, E, energies);
    hipLaunchKernelGGL(k_ctx,   dim3(16, B_),    dim3(256), 0, stream, E, energies, out);
}

// Round 16
// 258.682 us; speedup vs baseline: 1.0416x; 1.0416x over previous
//
#include <hip/hip_runtime.h>

#define B_ 32
#define L_ 2048
#define C1 512      // conv1 out channels (2C)
#define C2 256      // conv2 out channels
#define KW 15
#define P1 2034     // conv1 valid positions (L-14)
#define NJ 2016     // conv2 positions actually used (pos 2..2017)
#define NSEC 252
#define GOD 256

typedef _Float16 f16;
typedef __attribute__((ext_vector_type(4))) _Float16 f16x4;
typedef __attribute__((ext_vector_type(8))) _Float16 f16x8;
typedef __attribute__((ext_vector_type(4))) float f32x4;

// workspace byte offsets
#define WS_Y1T   0ull                       // f16 [32][2034][512]  = 66,650,112 B
#define WS_W2R   66650112ull                // f16 [15][256][512]   =  3,932,160 B
#define WS_W1R   70582272ull                // f16 [512][104]       =    106,496 B
#define WS_E     70688768ull                // f16 [32][256][2016]  = 33,030,144 B
#define WS_V     103718912ull               // f32 [32][2048]       =    262,144 B
#define WS_EN    103981056ull               // f32 [32][252]        =     32,256 B

__device__ __forceinline__ void gl16(const f16* g, f16* l) {
    __builtin_amdgcn_global_load_lds((const __attribute__((address_space(1))) char*)(g),
                                     (__attribute__((address_space(3))) char*)(l), 16, 0, 0);
}

// ---------------- prep | k_v fused (zero-LDS roles, concurrent) ----------------
//   [0,512)  : w2[o][c][k] f32 -> w2r[k][o][c] f16 ; w1 -> w1r[o][104] ; energies = 0
//   [512,768): v[b][p] = go_table[goidx[b]] . attn_w[:,p]
__global__ __launch_bounds__(256) void k_prep(const float* __restrict__ w2,
                                              f16* __restrict__ w2r,
                                              const float* __restrict__ w1,
                                              f16* __restrict__ w1r,
                                              float* __restrict__ energies,
                                              const int* __restrict__ goidx,
                                              const float* __restrict__ go_table,
                                              const float* __restrict__ attn_w,
                                              float* __restrict__ v) {
    const int bid = blockIdx.x;
    const int tid = threadIdx.x;
    if (bid < 512) {
        const int t0 = bid * 256 + tid;
        const int nthr = 512 * 256;
        for (int idx = t0; idx < C2 * C1 * KW; idx += nthr) {
            int o = idx / (C1 * KW);
            int rem = idx - o * (C1 * KW);
            int c = rem / KW;
            int k = rem - c * KW;
            w2r[((size_t)k * C2 + o) * C1 + c] = (f16)w2[idx];
        }
        for (int idx = t0; idx < C1 * 104; idx += nthr) {
            int o = idx / 104;
            int col = idx - o * 104;
            int e = col >> 4, k = col & 15;
            float val = (e < 5 && k < 15) ? w1[o * 75 + e * 15 + k] : 0.f;
            w1r[idx] = (f16)val;
        }
        for (int idx = t0; idx < B_ * NSEC; idx += nthr) energies[idx] = 0.f;
        return;
    }
    // k_v role
    const int r = bid - 512;
    const int b = r >> 3;
    const int p = (r & 7) * 256 + tid;
    const float* go = go_table + (size_t)goidx[b] * GOD;
    float acc = 0.f;
    for (int g = 0; g < GOD; ++g) acc = fmaf(go[g], attn_w[g * 2048 + p], acc);
    v[b * 2048 + p] = acc;
}

// ---------------- conv1 as MFMA implicit GEMM -> y1t[b][pos][o] f16 ----------------
// r12 body + LDS-staged coalesced store epilogue (16B rows). (r14, validated)
__global__ __launch_bounds__(256) void k_conv1(const int* __restrict__ seq,
                                               const float* __restrict__ aa_emb,
                                               const f16* __restrict__ w1r,
                                               const float* __restrict__ b1,
                                               f16* __restrict__ y1t) {
    __shared__ f16 Aw[256 * 104];   // 52 KB weights, rows 208 B; reused as output tile
    __shared__ f16 Bx[64 * 104];    // 13 KB, rows 208 B
    __shared__ float xs[5][80];
    const int b = blockIdx.z, o0 = blockIdx.y * 256, pos0 = blockIdx.x * 64;
    const int tid = threadIdx.x;
    const int wave = tid >> 6, lane = tid & 63;
    const int lm = lane & 15, lh = lane >> 4;
    const int half = blockIdx.y;

#pragma unroll
    for (int r = 0; r < 13; ++r) {
        int q = r * 4096 + wave * 1024 + lane * 16;
        gl16(w1r + o0 * 104 + (q >> 1), Aw + (q >> 1));
    }
    if (tid < 79) {
        int l = pos0 + tid;
        if (l < L_) {
            int a = seq[b * L_ + l];
#pragma unroll
            for (int e = 0; e < 5; ++e) xs[e][tid] = aa_emb[a * 5 + e];
        } else {
#pragma unroll
            for (int e = 0; e < 5; ++e) xs[e][tid] = 0.f;
        }
    }
    __syncthreads();
    for (int idx = tid; idx < 64 * 104; idx += 256) {
        int j = idx / 104, col = idx - j * 104;
        int e = col >> 4, k = col & 15;
        Bx[idx] = (e < 5 && k < 15) ? (f16)xs[e][j + k] : (f16)0.f;
    }
    __syncthreads();

    f32x4 acc[4][4];
#pragma unroll
    for (int mf = 0; mf < 4; ++mf)
#pragma unroll
        for (int nf = 0; nf < 4; ++nf) acc[mf][nf] = (f32x4){0.f, 0.f, 0.f, 0.f};

    const char* Ab = (const char*)Aw + (wave * 64 + lm) * 208 + lh * 16;
    const char* Bb = (const char*)Bx + lm * 208 + lh * 16;
#pragma unroll
    for (int ks = 0; ks < 3; ++ks) {
        f16x8 av[4], bv[4];
#pragma unroll
        for (int mf = 0; mf < 4; ++mf) av[mf] = *(const f16x8*)(Ab + mf * 16 * 208 + ks * 64);
#pragma unroll
        for (int nf = 0; nf < 4; ++nf) bv[nf] = *(const f16x8*)(Bb + nf * 16 * 208 + ks * 64);
#pragma unroll
        for (int mf = 0; mf < 4; ++mf)
#pragma unroll
            for (int nf = 0; nf < 4; ++nf)
                acc[mf][nf] = __builtin_amdgcn_mfma_f32_16x16x32_f16(av[mf], bv[nf], acc[mf][nf], 0, 0, 0);
    }

    // epilogue: stage tile in LDS (reuse Aw; [64 pos][264 f16] rows) -> 16B coalesced stores
    __syncthreads();   // done reading Aw frags
    {
        f16* Ot = Aw;  // 64*264 = 16896 f16 <= 26624
#pragma unroll
        for (int nf = 0; nf < 4; ++nf) {
            int pos = nf * 16 + lm;
#pragma unroll
            for (int mf = 0; mf < 4; ++mf) {
                int ob = wave * 64 + mf * 16 + lh * 4;
                f16x4 st;
#pragma unroll
                for (int rr = 0; rr < 4; ++rr)
                    st[rr] = (f16)fmaxf(acc[mf][nf][rr] + b1[o0 + ob + rr], 0.f);
                *(f16x4*)(Ot + pos * 264 + ob) = st;
            }
        }
    }
    __syncthreads();
#pragma unroll
    for (int rr = 0; rr < 8; ++rr) {
        int q = rr * 4096 + tid * 16;          // byte index in 32KB logical tile
        int pos = q >> 9;                      // /512B
        int ob = q & 511;
        if (pos0 + pos < P1)
            *(f16x8*)((char*)y1t + (size_t)(b * P1 + pos0 + pos) * 1024 + half * 512 + ob) =
                *(const f16x8*)((const char*)Aw + pos * 528 + ob);
    }
}

// ---------------- conv2 implicit GEMM, 2 barrier domains per CU (r12, validated) ----------------
// grid (16 n-tiles of 128, 32 b) = 512 blocks; block 256 = 4 waves (2M x 2N),
// wave tile 128x64. LDS 68 KB -> 2 blocks/CU (independent barrier domains; m114).
// 240 tiles of BK=32. A: 3-deep rotating 16KB slots, staged 2 tiles ahead, published
// by counted vmcnt(4) + ONE end-barrier per tile. B: single 20KB buffer per cc
// (15-tap reuse), restaged at cc boundary behind vmcnt(4)+barrier.
// Swizzles (verified r7-r14): A slot16 ^= (row>>1)&3 ; B slot16 ^= row&7.
__global__ __launch_bounds__(256, 2) void k_conv2(const f16* __restrict__ y1t,
                                                  const f16* __restrict__ w2r,
                                                  const float* __restrict__ b2,
                                                  const float* __restrict__ v,
                                                  f16* __restrict__ E,
                                                  float* __restrict__ energies) {
    __shared__ f16 As[3 * 8192];    // 48 KB: 3 slots [256 o][32 c]
    __shared__ f16 Bs[10240];       // 20 KB: [160 n][64 c]
    const int b = blockIdx.y;
    const int n0 = blockIdx.x << 7;
    const int tid = threadIdx.x;
    const int wave = tid >> 6, lane = tid & 63;
    const int lm = lane & 15, lh = lane >> 4;
    const int wm = wave >> 1, wn = wave & 1;
    const size_t ybase = (size_t)b * P1 + n0 + 2;

    f32x4 acc[8][4];
#pragma unroll
    for (int mf = 0; mf < 8; ++mf)
#pragma unroll
        for (int nf = 0; nf < 4; ++nf) acc[mf][nf] = (f32x4){0.f, 0.f, 0.f, 0.f};

#define STAGE_A(slot, cc2, k2, h2)                                                    \
    {                                                                                 \
        _Pragma("unroll")                                                             \
        for (int rr = 0; rr < 4; ++rr) {                                              \
            int q = rr * 4096 + tid * 16;                                             \
            int row = q >> 6;                                                         \
            int sw = ((q >> 4) & 3) ^ ((row >> 1) & 3);                               \
            const f16* g = w2r + (size_t)(k2) * 131072 + row * C1 + (cc2) * 64 + (h2) * 32 + sw * 8; \
            gl16(g, As + (slot) * 8192 + (q >> 1));                                   \
        }                                                                             \
    }
#define STAGE_B(cc2)                                                                  \
    {                                                                                 \
        _Pragma("unroll")                                                             \
        for (int rr = 0; rr < 5; ++rr) {                                              \
            int q = rr * 4096 + tid * 16;                                             \
            int row = q >> 7;                                                         \
            int sw = ((q >> 4) & 7) ^ (row & 7);                                      \
            const f16* g = y1t + (ybase + row) * C1 + (cc2) * 64 + sw * 8;            \
            gl16(g, Bs + (q >> 1));                                                   \
        }                                                                             \
    }

    // prologue: B(cc0) + A tiles 0,1 into slots 0,1; publish B + slot0 (leave slot1's 4)
    STAGE_B(0);
    STAGE_A(0, 0, 0, 0);
    STAGE_A(1, 0, 0, 1);
    asm volatile("s_waitcnt vmcnt(4)" ::: "memory");
    __builtin_amdgcn_s_barrier();

    const int swA = (lh ^ ((lm >> 1) & 3)) << 4;   // A read swizzle (byte)
    int sl = 0;                                    // tile t -> slot t%3

#pragma unroll 1
    for (int cc = 0; cc < 8; ++cc) {
#pragma unroll 1
        for (int k = 0; k < KW; ++k) {
#pragma unroll
            for (int h = 0; h < 2; ++h) {
                int k2 = k + 1, cc2 = cc;
                if (k2 == 15) { k2 = 0; cc2 = cc + 1; }
                const bool have2 = (cc2 < 8);
                const bool bnd = (k == 0 && h == 0 && cc > 0);
                const int s2 = (sl >= 1) ? sl - 1 : 2;   // (sl+2)%3

                if (bnd) {
                    // all B-reads of cc-1 completed before the previous end-barrier
                    STAGE_B(cc);
                    STAGE_A(s2, cc2, k2, h);   // this tile's stage, issued early
                    asm volatile("s_waitcnt vmcnt(4)" ::: "memory");  // B + prev slot published
                    __builtin_amdgcn_s_barrier();
                }

                const char* Ab = (const char*)As + sl * 16384;
                f16x8 bv[4], av[8];
#pragma unroll
                for (int nf = 0; nf < 4; ++nf) {
                    int brow = wn * 64 + nf * 16 + lm + k;
                    bv[nf] = *(const f16x8*)((const char*)Bs + brow * 128 + ((((h << 2) | lh) ^ (brow & 7)) << 4));
                }
#pragma unroll
                for (int i = 0; i < 8; ++i)
                    av[i] = *(const f16x8*)(Ab + (wm * 128 + i * 16 + lm) * 64 + swA);
                if (!bnd && have2) STAGE_A(s2, cc2, k2, h);

                __builtin_amdgcn_s_setprio(1);
#pragma unroll
                for (int i = 0; i < 8; ++i)
#pragma unroll
                    for (int nf = 0; nf < 4; ++nf)
                        acc[i][nf] = __builtin_amdgcn_mfma_f32_16x16x32_f16(av[i], bv[nf], acc[i][nf], 0, 0, 0);
                __builtin_amdgcn_s_setprio(0);
                if (have2) { asm volatile("s_waitcnt vmcnt(4)" ::: "memory"); }
                else       { asm volatile("s_waitcnt vmcnt(0)" ::: "memory"); }
                __builtin_amdgcn_s_barrier();

                sl = (sl == 2) ? 0 : sl + 1;
            }
        }
    }

    // epilogue: E store (bias+relu, f16) + fused energy partials
    const float* vb = v + b * 2048;
#pragma unroll
    for (int nf = 0; nf < 4; ++nf) {
        const int j = n0 + wn * 64 + nf * 16 + lm;
        if (j >= NJ) continue;
        const int jq = j / NSEC;
        const int jm = j - jq * NSEC;
        float esum = 0.f;
#pragma unroll
        for (int mf = 0; mf < 8; ++mf) {
            const int ob = wm * 128 + mf * 16 + lh * 4;
#pragma unroll
            for (int r = 0; r < 4; ++r) {
                float val = fmaxf(acc[mf][nf][r] + b2[ob + r], 0.f);
                E[((size_t)b * C2 + ob + r) * NJ + j] = (f16)val;
                esum = fmaf(val, vb[(ob + r) * 8 + jq], esum);
            }
        }
        atomicAdd(&energies[b * NSEC + jm], esum);
    }
#undef STAGE_A
#undef STAGE_B
}

// ---------------- ctx with fused softmax (r14, validated: one channel per wave) ----------------
__global__ __launch_bounds__(256) void k_ctx(const f16* __restrict__ E,
                                             const float* __restrict__ energies,
                                             float* __restrict__ out) {
    __shared__ float red[256];
    __shared__ float attn_s[NSEC];
    const int b = blockIdx.y;
    const int tid = threadIdx.x;

    float ev = 0.f, e = -1e30f;
    if (tid < NSEC) { ev = energies[b * NSEC + tid]; e = ev; }
    red[tid] = e;
    __syncthreads();
    for (int s = 128; s > 0; s >>= 1) {
        if (tid < s) red[tid] = fmaxf(red[tid], red[tid + s]);
        __syncthreads();
    }
    float m = red[0];
    __syncthreads();
    float ex = (tid < NSEC) ? __expf(ev - m) : 0.f;
    red[tid] = ex;
    __syncthreads();
    for (int s = 128; s > 0; s >>= 1) {
        if (tid < s) red[tid] += red[tid + s];
        __syncthreads();
    }
    float inv = 1.f / red[0];
    if (tid < NSEC) attn_s[tid] = ex * inv;
    __syncthreads();

    const int wave = tid >> 6, lane = tid & 63;
    const int c = blockIdx.x * 4 + wave;
    float a0 = 0.f, a1 = 0.f, a2 = 0.f, a3 = 0.f;
    if (lane < 63) {
        a0 = attn_s[lane * 4];     a1 = attn_s[lane * 4 + 1];
        a2 = attn_s[lane * 4 + 2]; a3 = attn_s[lane * 4 + 3];
    }
    const f16* Er = E + ((size_t)b * C2 + c) * NJ;
#pragma unroll
    for (int r = 0; r < 8; ++r) {
        float s = 0.f;
        if (lane < 63) {
            f16x4 ee = *(const f16x4*)(Er + r * NSEC + lane * 4);
            s = (float)ee[0] * a0 + (float)ee[1] * a1 + (float)ee[2] * a2 + (float)ee[3] * a3;
        }
#pragma unroll
        for (int off = 32; off > 0; off >>= 1) s += __shfl_down(s, off);
        if (lane == 0) out[b * 2048 + c * 8 + r] = s;
    }
}

extern "C" void kernel_launch(void* const* d_in, const int* in_sizes, int n_in,
                              void* d_out, int out_size, void* d_ws, size_t ws_size,
                              hipStream_t stream) {
    const int*   seq      = (const int*)d_in[0];
    const int*   goidx    = (const int*)d_in[1];
    const float* aa_emb   = (const float*)d_in[2];
    const float* w1       = (const float*)d_in[3];
    const float* b1       = (const float*)d_in[4];
    const float* w2       = (const float*)d_in[5];
    const float* b2       = (const float*)d_in[6];
    const float* go_table = (const float*)d_in[7];
    const float* attn_w   = (const float*)d_in[8];
    float* out = (float*)d_out;

    char* ws = (char*)d_ws;
    f16*   y1t      = (f16*)(ws + WS_Y1T);
    f16*   w2r      = (f16*)(ws + WS_W2R);
    f16*   w1r      = (f16*)(ws + WS_W1R);
    f16*   E        = (f16*)(ws + WS_E);
    float* v        = (float*)(ws + WS_V);
    float* energies = (float*)(ws + WS_EN);

    hipLaunchKernelGGL(k_prep,  dim3(768),       dim3(256), 0, stream,
                       w2, w2r, w1, w1r, energies, goidx, go_table, attn_w, v);
    hipLaunchKernelGGL(k_conv1, dim3(32, 2, B_), dim3(256), 0, stream, seq, aa_emb, w1r, b1, y1t);
    hipLaunchKernelGGL(k_conv2, dim3(16, B_),    dim3(256), 0, stream, y1t, w2r, b2, v, E, energies);
    hipLaunchKernelGGL(k_ctx,   dim3(64, B_),    dim3(256), 0, stream, E, energies, out);
}